// Round 9
// baseline (21.926 us; speedup 1.0000x reference)
//
#include <hip/hip_runtime.h>

// DLGN_VT v7 — scalar-pipe offload:
//   K1 gates: lane = batch row. Block = (bg: 64 rows) x (fq: 12 features); wave = k-quarter.
//     x-quarter in 32 VGPRs (per-lane gather from L2/L3). W rows are wave-UNIFORM ->
//     s_load + v_fma(sgpr, vgpr, vgpr): no LDS, no W staging in the inner loop.
//     k-quarter partials combined in padded LDS (stride 13, conflict-free), sigmoid,
//     coalesced store of G[b][96] to d_ws.
//   K2 contract: v6 structure (V in 32 float4 regs, thread=(j,kchunk), i-first u4),
//     but g1[b][i] read via wave-uniform GLOBAL loads (s_load) instead of 8 LDS b128
//     reads per (wave,b); g2/g3 from small LDS tile; shfl_xor reduce -> out.
// No atomics, no memset.

#define BETA 30.0f

__device__ __forceinline__ float f4c(const float4 v, int c) {
    // compile-time c after full unroll -> folds to a register pick
    return c == 0 ? v.x : (c == 1 ? v.y : (c == 2 ? v.z : v.w));
}

// ---------------- K1: gates (lane = batch row, W via scalar loads) ----------------
__global__ __launch_bounds__(256, 2) void gates_v7_kernel(
    const float* __restrict__ x,
    const float* __restrict__ W1,
    const float* __restrict__ W2,
    const float* __restrict__ W3,
    float* __restrict__ G)
{
    __shared__ float Pscr[4][64 * 13];   // 13312 B; stride 13 (odd) -> conflict-free writes

    const int t    = threadIdx.x;
    const int lane = t & 63;
    const int wv   = __builtin_amdgcn_readfirstlane(t >> 6);   // k-quarter, wave-uniform
    const int bid  = blockIdx.x;          // 512 blocks
    const int bg   = bid >> 3;            // [0,64)
    const int fq   = bid & 7;             // [0,8) -> features fq*12 .. fq*12+11
    const int b0   = bg * 64;
    const int fb   = fq * 12;

    // x quarter for this lane's row -> 32 VGPRs (per-lane gather; x is L3-resident)
    const float4* xrow = (const float4*)(x + (size_t)(b0 + lane) * 128 + wv * 32);
    float xr[32];
#pragma unroll
    for (int c = 0; c < 8; ++c) {
        const float4 xv = xrow[c];
        xr[4 * c + 0] = xv.x; xr[4 * c + 1] = xv.y;
        xr[4 * c + 2] = xv.z; xr[4 * c + 3] = xv.w;
    }

    // 12 features: W pointer wave-uniform -> scalar loads feed v_fma(sgpr, vgpr, vgpr)
    float acc[12];
#pragma unroll
    for (int fl = 0; fl < 12; ++fl) {
        const int f = fb + fl;            // runtime but wave-uniform
        const float* Wr = (f < 32) ? (W1 + f * 128)
                        : (f < 64) ? (W2 + (f - 32) * 128)
                                   : (W3 + (f - 64) * 128);
        const float* wq = Wr + wv * 32;   // uniform
        float a = 0.f;
#pragma unroll
        for (int c = 0; c < 32; ++c)
            a = fmaf(wq[c], xr[c], a);
        acc[fl] = a;
    }

    // combine 4 k-quarters in LDS
    float* ps = &Pscr[wv][lane * 13];
#pragma unroll
    for (int fl = 0; fl < 12; ++fl) ps[fl] = acc[fl];
    __syncthreads();

    // 64 b x 12 f = 768 outputs, 3 per thread; o-order -> coalesced G writes (12-float runs)
#pragma unroll
    for (int q = 0; q < 3; ++q) {
        const int o  = q * 256 + t;       // [0,768)
        const int b  = o / 12;
        const int fl = o - b * 12;
        const float a = Pscr[0][b * 13 + fl] + Pscr[1][b * 13 + fl]
                      + Pscr[2][b * 13 + fl] + Pscr[3][b * 13 + fl];
        G[(size_t)(b0 + b) * 96 + fb + fl] = 1.0f / (1.0f + __expf(-BETA * a));
    }
}

// ---------------- K2: contraction (g1 via scalar loads) ----------------
__global__ __launch_bounds__(256, 2) void contract_v7_kernel(
    const float* __restrict__ G,
    const float* __restrict__ V,
    float* __restrict__ out)
{
    __shared__ float Gs[8][100];   // g2/g3 tile (stride 100, conflict-checked)
    __shared__ float red[4][8];

    const int t  = threadIdx.x;
    const int b0 = blockIdx.x * 8;

    // V[i][j][4c2..4c2+3] for all i -> 32 float4 regs; coalesced, disjoint per thread
    const float4* V4 = (const float4*)V;
    float4 v[32];
#pragma unroll
    for (int i = 0; i < 32; ++i) v[i] = V4[i * 256 + t];

    // stage G tile (8 rows x 96 = 192 float4), coalesced
    if (t < 192) {
        const float4 gv = ((const float4*)(G + (size_t)b0 * 96))[t];
        const int b   = t / 24;
        const int f4i = t - b * 24;
        *(float4*)&Gs[b][f4i * 4] = gv;
    }
    __syncthreads();

    const int j  = t >> 3;   // [0,32)
    const int c2 = t & 7;    // [0,8)
    const int w  = t >> 6;
    const int l  = t & 63;

    for (int b = 0; b < 8; ++b) {          // runtime loop: regs recycle, no hoist
        const float* gb = G + (size_t)(b0 + b) * 96;            // uniform -> s_load
        const float4 g3r = *(const float4*)&Gs[b][64 + c2 * 4]; // per-lane, LDS
        const float  g2s = Gs[b][32 + j];                       // per-lane, LDS

        // i-first: u4 = sum_i g1[i] * v[i]; g1[i] is a scalar (SGPR) operand
        float ux = 0.f, uy = 0.f, uz = 0.f, uw = 0.f;
#pragma unroll
        for (int i = 0; i < 32; ++i) {
            const float g1i = gb[i];
            ux = fmaf(g1i, v[i].x, ux);
            uy = fmaf(g1i, v[i].y, uy);
            uz = fmaf(g1i, v[i].z, uz);
            uw = fmaf(g1i, v[i].w, uw);
        }
        float s = ux * g3r.x;
        s = fmaf(uy, g3r.y, s);
        s = fmaf(uz, g3r.z, s);
        s = fmaf(uw, g3r.w, s);
        float p = s * g2s;

        p += __shfl_xor(p, 1);
        p += __shfl_xor(p, 2);
        p += __shfl_xor(p, 4);
        p += __shfl_xor(p, 8);
        p += __shfl_xor(p, 16);
        p += __shfl_xor(p, 32);
        if (l == 0) red[w][b] = p;
    }
    __syncthreads();

    if (t < 8) out[b0 + t] = red[0][t] + red[1][t] + red[2][t] + red[3][t];
}

extern "C" void kernel_launch(void* const* d_in, const int* in_sizes, int n_in,
                              void* d_out, int out_size, void* d_ws, size_t ws_size,
                              hipStream_t stream) {
    const float* x  = (const float*)d_in[0];
    const float* W1 = (const float*)d_in[1];
    const float* W2 = (const float*)d_in[2];
    const float* W3 = (const float*)d_in[3];
    const float* V  = (const float*)d_in[4];
    float* out = (float*)d_out;
    float* G   = (float*)d_ws;   // 4096*96*4 = 1.5 MB scratch

    gates_v7_kernel<<<dim3(512), dim3(256), 0, stream>>>(x, W1, W2, W3, G);
    contract_v7_kernel<<<dim3(512), dim3(256), 0, stream>>>(G, V, out);
}